// Round 1
// baseline (9.733 us; speedup 1.0000x reference)
//
#include <hip/hip_runtime.h>

#define THRESH 0.24f
#define DCLS 127      // CLASS_NUM - 1
#define BATCH 8192

// One 64-lane wave per sample row. dist to one-hot row j = S + 1 - 2*x[j],
// so argmin(dist) == argmax(x) with first-index tie-break.
__global__ __launch_bounds__(256) void ohz_classify_kernel(
    const float* __restrict__ x, int* __restrict__ out, int batch) {
    const int wave = (int)((blockIdx.x * blockDim.x + threadIdx.x) >> 6);
    const int lane = (int)(threadIdx.x & 63);
    if (wave >= batch) return;

    const float* row = x + (size_t)wave * DCLS;

    // lane covers elements {lane, lane+64}; element 127 doesn't exist (D=127)
    float a = row[lane];
    float b = (lane < DCLS - 64) ? row[lane + 64] : -1.0f;  // sentinel < any x

    float bv; int bi;
    if (b > a) { bv = b; bi = lane + 64; }   // strict > keeps lower index on tie
    else       { bv = a; bi = lane; }

    bool below = (a < THRESH) && ((lane >= DCLS - 64) || (b < THRESH));

    // 64-lane butterfly reduce: max value, tie -> min index (assoc+comm)
    #pragma unroll
    for (int off = 32; off >= 1; off >>= 1) {
        float ov = __shfl_xor(bv, off, 64);
        int   oi = __shfl_xor(bi, off, 64);
        if (ov > bv || (ov == bv && oi < bi)) { bv = ov; bi = oi; }
    }

    bool allb = __all(below);

    if (lane == 0) out[wave] = allb ? 0 : (bi + 1);
}

extern "C" void kernel_launch(void* const* d_in, const int* in_sizes, int n_in,
                              void* d_out, int out_size, void* d_ws, size_t ws_size,
                              hipStream_t stream) {
    const float* x = (const float*)d_in[0];
    // d_in[1] (classes) is the identity matrix by construction — unused.
    int* out = (int*)d_out;
    const int batch = out_size;  // 8192

    const int threads = 256;                       // 4 waves/block
    const int waves_per_block = threads / 64;
    const int blocks = (batch + waves_per_block - 1) / waves_per_block;
    ohz_classify_kernel<<<blocks, threads, 0, stream>>>(x, out, batch);
}